// Round 13
// baseline (54.484 us; speedup 1.0000x reference)
//
#include <hip/hip_runtime.h>
#include <hip/hip_bf16.h>

#define IN_F 16
#define OUT_F 8

typedef float v4f __attribute__((ext_vector_type(4)));

__global__ __launch_bounds__(256) void fq_linear_kernel(
    const float* __restrict__ x,
    const float* __restrict__ w,
    const float* __restrict__ in_scale_p,
    const float* __restrict__ out_scale_p,
    float* __restrict__ out,
    int B)
{
    // torch-style fake-quant: round(v * (1/scale)), not round(v / scale).
    // NUMERICS FROZEN (bit-exact vs ref as of R11) — only cache hints changed.
    #pragma clang fp contract(off)

    __shared__ float s_wq[OUT_F * IN_F];
    __shared__ float s_ws[OUT_F];

    const int tid = threadIdx.x;

    // --- per-block (redundant, tiny) weight fake-quant into LDS (f32) ---
    if (tid < OUT_F) {
        float m = 0.0f;
        #pragma unroll
        for (int i = 0; i < IN_F; ++i) m = fmaxf(m, fabsf(w[tid * IN_F + i]));
        // scale computation is explicit jax code: true f32 division by 7
        s_ws[tid] = fmaxf(m / 7.0f, 1e-9f);
    }
    __syncthreads();
    if (tid < OUT_F * IN_F) {
        float ws  = s_ws[tid >> 4];
        float rws = 1.0f / ws;                 // correctly-rounded f32 reciprocal
        float q   = fminf(fmaxf(rintf(w[tid] * rws), -8.0f), 7.0f);
        s_wq[tid] = q * ws;
    }
    __syncthreads();

    const float in_s    = *in_scale_p;
    const float out_s   = *out_scale_p;
    const float inv_in  = 1.0f / in_s;         // = 20.0f exactly
    const float inv_out = 1.0f / out_s;        // = 10.0f exactly

    const int row = blockIdx.x * 256 + tid;
    if (row >= B) return;

    // --- load one row of x (16 fp32 = 4x dwordx4), nontemporal (read-once) ---
    const v4f* xv = reinterpret_cast<const v4f*>(x) + (size_t)row * 4;
    v4f a0 = __builtin_nontemporal_load(xv + 0);
    v4f a1 = __builtin_nontemporal_load(xv + 1);
    v4f a2 = __builtin_nontemporal_load(xv + 2);
    v4f a3 = __builtin_nontemporal_load(xv + 3);
    float xr[IN_F] = { a0.x, a0.y, a0.z, a0.w,
                       a1.x, a1.y, a1.z, a1.w,
                       a2.x, a2.y, a2.z, a2.w,
                       a3.x, a3.y, a3.z, a3.w };

    // --- static int8 fake-quant of input: round(x * inv_scale), RNE ---
    float xq[IN_F];
    #pragma unroll
    for (int i = 0; i < IN_F; ++i) {
        float v = xr[i] * inv_in;
        asm volatile("" : "+v"(v));            // keep the mul un-contracted
        float q = fminf(fmaxf(rintf(v), -128.0f), 127.0f);
        xq[i] = q * in_s;
    }

    // --- 8 outputs: sequential ascending-k fused-FMA chain ---
    float ob[OUT_F];
    #pragma unroll
    for (int o = 0; o < OUT_F; ++o) {
        float acc = 0.0f;
        #pragma unroll
        for (int i = 0; i < IN_F; ++i)
            acc = fmaf(xq[i], s_wq[o * IN_F + i], acc);
        float v = acc * inv_out;
        asm volatile("" : "+v"(v));
        float q = fminf(fmaxf(rintf(v), -128.0f), 127.0f);
        ob[o] = q * out_s;
    }

    // --- store 8 fp32 = 32B contiguous per row, nontemporal (write-once) ---
    v4f* ov = reinterpret_cast<v4f*>(out) + (size_t)row * 2;
    v4f o0 = { ob[0], ob[1], ob[2], ob[3] };
    v4f o1 = { ob[4], ob[5], ob[6], ob[7] };
    __builtin_nontemporal_store(o0, ov + 0);
    __builtin_nontemporal_store(o1, ov + 1);
}

extern "C" void kernel_launch(void* const* d_in, const int* in_sizes, int n_in,
                              void* d_out, int out_size, void* d_ws, size_t ws_size,
                              hipStream_t stream) {
    const float* x     = (const float*)d_in[0];
    const float* w     = (const float*)d_in[1];
    const float* in_s  = (const float*)d_in[2];
    const float* out_s = (const float*)d_in[3];
    float* out = (float*)d_out;

    const int B = in_sizes[0] / IN_F;
    const int blocks = (B + 255) / 256;
    fq_linear_kernel<<<blocks, 256, 0, stream>>>(x, w, in_s, out_s, out, B);
}

// Round 14
// 34.367 us; speedup vs baseline: 1.5853x; 1.5853x over previous
//
#include <hip/hip_runtime.h>
#include <hip/hip_bf16.h>

#define IN_F 16
#define OUT_F 8

__global__ __launch_bounds__(256) void fq_linear_kernel(
    const float* __restrict__ x,
    const float* __restrict__ w,
    const float* __restrict__ in_scale_p,
    const float* __restrict__ out_scale_p,
    float* __restrict__ out,
    int B)
{
    // torch-style fake-quant: round(v * (1/scale)), not round(v / scale).
    // NUMERICS FROZEN (bit-exact vs ref as of R11). R13's nontemporal hints
    // REGRESSED (34.4 -> 54.5 us) — reverted to plain cached vector loads.
    #pragma clang fp contract(off)

    __shared__ float s_wq[OUT_F * IN_F];
    __shared__ float s_ws[OUT_F];

    const int tid = threadIdx.x;

    // --- per-block (redundant, tiny) weight fake-quant into LDS (f32) ---
    if (tid < OUT_F) {
        float m = 0.0f;
        #pragma unroll
        for (int i = 0; i < IN_F; ++i) m = fmaxf(m, fabsf(w[tid * IN_F + i]));
        // scale computation is explicit jax code: true f32 division by 7
        s_ws[tid] = fmaxf(m / 7.0f, 1e-9f);
    }
    __syncthreads();
    if (tid < OUT_F * IN_F) {
        float ws  = s_ws[tid >> 4];
        float rws = 1.0f / ws;                 // correctly-rounded f32 reciprocal
        float q   = fminf(fmaxf(rintf(w[tid] * rws), -8.0f), 7.0f);
        s_wq[tid] = q * ws;
    }
    __syncthreads();

    const float in_s    = *in_scale_p;
    const float out_s   = *out_scale_p;
    const float inv_in  = 1.0f / in_s;         // = 20.0f exactly
    const float inv_out = 1.0f / out_s;        // = 10.0f exactly

    const int row = blockIdx.x * 256 + tid;
    if (row >= B) return;

    // --- load one row of x (16 fp32 = 4x float4) ---
    const float4* xv = reinterpret_cast<const float4*>(x) + (size_t)row * 4;
    float4 a0 = xv[0], a1 = xv[1], a2 = xv[2], a3 = xv[3];
    float xr[IN_F] = { a0.x, a0.y, a0.z, a0.w,
                       a1.x, a1.y, a1.z, a1.w,
                       a2.x, a2.y, a2.z, a2.w,
                       a3.x, a3.y, a3.z, a3.w };

    // --- static int8 fake-quant of input: round(x * inv_scale), RNE ---
    float xq[IN_F];
    #pragma unroll
    for (int i = 0; i < IN_F; ++i) {
        float v = xr[i] * inv_in;
        asm volatile("" : "+v"(v));            // keep the mul un-contracted
        float q = fminf(fmaxf(rintf(v), -128.0f), 127.0f);
        xq[i] = q * in_s;
    }

    // --- 8 outputs: sequential ascending-k fused-FMA chain ---
    float ob[OUT_F];
    #pragma unroll
    for (int o = 0; o < OUT_F; ++o) {
        float acc = 0.0f;
        #pragma unroll
        for (int i = 0; i < IN_F; ++i)
            acc = fmaf(xq[i], s_wq[o * IN_F + i], acc);
        float v = acc * inv_out;
        asm volatile("" : "+v"(v));
        float q = fminf(fmaxf(rintf(v), -128.0f), 127.0f);
        ob[o] = q * out_s;
    }

    // --- store 8 fp32 = 32B contiguous per row (two float4 stores) ---
    float4* ov = reinterpret_cast<float4*>(out) + (size_t)row * 2;
    ov[0] = make_float4(ob[0], ob[1], ob[2], ob[3]);
    ov[1] = make_float4(ob[4], ob[5], ob[6], ob[7]);
}

extern "C" void kernel_launch(void* const* d_in, const int* in_sizes, int n_in,
                              void* d_out, int out_size, void* d_ws, size_t ws_size,
                              hipStream_t stream) {
    const float* x     = (const float*)d_in[0];
    const float* w     = (const float*)d_in[1];
    const float* in_s  = (const float*)d_in[2];
    const float* out_s = (const float*)d_in[3];
    float* out = (float*)d_out;

    const int B = in_sizes[0] / IN_F;
    const int blocks = (B + 255) / 256;
    fq_linear_kernel<<<blocks, 256, 0, stream>>>(x, w, in_s, out_s, out, B);
}